// Round 6
// baseline (246.437 us; speedup 1.0000x reference)
//
#include <hip/hip_runtime.h>
#include <hip/hip_bf16.h>

typedef __hip_bfloat16 bf16;
typedef __attribute__((ext_vector_type(8))) short short8;
typedef __attribute__((ext_vector_type(4))) float f32x4;

#define NHD 16
#define HSD 64
#define KVLD 128
#define QLD 128
#define CD 1024
#define BD 2
#define TD 2048

__device__ __forceinline__ short8 ld8(const bf16* p) { return *(const short8*)p; }
__device__ __forceinline__ void st8(bf16* p, short8 v) { *(short8*)p = v; }

__device__ __forceinline__ short8 cvt8(float4 a, float4 b) {
    union { short8 s; bf16 h[8]; } u;
    u.h[0] = __float2bfloat16(a.x); u.h[1] = __float2bfloat16(a.y);
    u.h[2] = __float2bfloat16(a.z); u.h[3] = __float2bfloat16(a.w);
    u.h[4] = __float2bfloat16(b.x); u.h[5] = __float2bfloat16(b.y);
    u.h[6] = __float2bfloat16(b.z); u.h[7] = __float2bfloat16(b.w);
    return u.s;
}
__device__ __forceinline__ void st4(bf16* p, float4 a) {
    union { short4 s; bf16 h[4]; } u;
    u.h[0] = __float2bfloat16(a.x); u.h[1] = __float2bfloat16(a.y);
    u.h[2] = __float2bfloat16(a.z); u.h[3] = __float2bfloat16(a.w);
    *(short4*)p = u.s;
}
__device__ __forceinline__ void st4f(bf16* p, f32x4 a) {
    union { short4 s; bf16 h[4]; } u;
    u.h[0] = __float2bfloat16(a[0]); u.h[1] = __float2bfloat16(a[1]);
    u.h[2] = __float2bfloat16(a[2]); u.h[3] = __float2bfloat16(a[3]);
    *(short4*)p = u.s;
}

// ---------------------------------------------------------------------------
// Launch 1: k_pre — 256 blocks, batch-8 register load groups.
//   [0,128):   M1 partials  m1p[part](i,j) = sum_{c chunk} wuq(c,i)*wuk(c,j)
//   [128,256): G[h](p,i) = sum_{d<64} wdq(p, h*64+d) * wuq(h*64+d, i)
// (bf16 weight-panel role removed: proj converts inline — one less dependency)
// ---------------------------------------------------------------------------
__global__ __launch_bounds__(256) void k_pre(const float* __restrict__ wuq,
                                             const float* __restrict__ wuk,
                                             const float* __restrict__ wdq,
                                             float* __restrict__ m1p,
                                             float* __restrict__ G) {
    const int b = blockIdx.x;
    const int tid = threadIdx.x;
    if (b < 128) {
        const int part = b >> 4, ig = b & 15;
        const int i = ig * 8 + (tid >> 5);
        const int j4 = (tid & 31) << 2;
        const float* wq = wuq + (size_t)part * 128 * QLD;
        const float* wk = wuk + (size_t)part * 128 * KVLD;
        float4 acc = make_float4(0.f, 0.f, 0.f, 0.f);
        for (int c0 = 0; c0 < 128; c0 += 8) {
            float a[8]; float4 kv[8];
#pragma unroll
            for (int u = 0; u < 8; ++u) {
                a[u] = wq[(c0 + u) * QLD + i];
                kv[u] = *(const float4*)(wk + (c0 + u) * KVLD + j4);
            }
#pragma unroll
            for (int u = 0; u < 8; ++u) {
                acc.x = fmaf(a[u], kv[u].x, acc.x);
                acc.y = fmaf(a[u], kv[u].y, acc.y);
                acc.z = fmaf(a[u], kv[u].z, acc.z);
                acc.w = fmaf(a[u], kv[u].w, acc.w);
            }
        }
        *(float4*)(m1p + (size_t)part * 16384 + (size_t)i * 128 + j4) = acc;
    } else {
        const int b1 = b - 128;
        const int h = b1 >> 3, p8 = b1 & 7;
        const int p = p8 * 16 + (tid >> 4);
        const int i8 = (tid & 15) << 3;
        float acc[8];
#pragma unroll
        for (int t = 0; t < 8; ++t) acc[t] = 0.f;
        const float* wdqp = wdq + (size_t)p * CD + h * 64;
        const float* wuqh = wuq + (size_t)(h * 64) * QLD + i8;
        for (int d0 = 0; d0 < 64; d0 += 8) {
            float a[8]; float4 b0[8], b1v[8];
#pragma unroll
            for (int u = 0; u < 8; ++u) {
                a[u] = wdqp[d0 + u];
                b0[u] = *(const float4*)(wuqh + (d0 + u) * QLD);
                b1v[u] = *(const float4*)(wuqh + (d0 + u) * QLD + 4);
            }
#pragma unroll
            for (int u = 0; u < 8; ++u) {
                acc[0] = fmaf(a[u], b0[u].x, acc[0]);  acc[1] = fmaf(a[u], b0[u].y, acc[1]);
                acc[2] = fmaf(a[u], b0[u].z, acc[2]);  acc[3] = fmaf(a[u], b0[u].w, acc[3]);
                acc[4] = fmaf(a[u], b1v[u].x, acc[4]); acc[5] = fmaf(a[u], b1v[u].y, acc[5]);
                acc[6] = fmaf(a[u], b1v[u].z, acc[6]); acc[7] = fmaf(a[u], b1v[u].w, acc[7]);
            }
        }
        float* dst = G + (size_t)h * 16384 + (size_t)p * 128 + i8;
        *(float4*)dst = make_float4(acc[0], acc[1], acc[2], acc[3]);
        *(float4*)(dst + 4) = make_float4(acc[4], acc[5], acc[6], acc[7]);
    }
}

// ---------------------------------------------------------------------------
// Launch 2: k_main — 768 blocks, three concurrent roles.
//   [0,256):   proj GEMM [Q1|ckv] = x @ [Wdq|Wdkv]^T, inline f32->bf16 convert
//   [256,512): Et_h = scale * (M1^T @ G_h); batch-8 loads
//   [512,768): veffT = Wo @ Wuv; wuv LDS-chunked, reg double-buffered, batch-8
// ---------------------------------------------------------------------------
__global__ __launch_bounds__(256) void k_main(const float* __restrict__ x,
                                              const float* __restrict__ wdq,
                                              const float* __restrict__ wdkv,
                                              const float* __restrict__ m1p,
                                              const float* __restrict__ G,
                                              const float* __restrict__ wuv,
                                              const float* __restrict__ wo,
                                              bf16* __restrict__ q1_bf,
                                              float* __restrict__ ckv_out,
                                              bf16* __restrict__ ckv_bf,
                                              bf16* __restrict__ ckvT_bf,
                                              bf16* __restrict__ Et_bf,
                                              bf16* __restrict__ veffT_bf) {
    __shared__ __align__(16) char arena[49152];
    const int blk = blockIdx.x;
    const int tid = threadIdx.x;

    if (blk < 256) {
        // ================= proj (inline convert + reg-prefetch) ==============
        const int m0 = blk * 16;
        const int w = tid >> 6, lane = tid & 63, m16 = lane & 15, g = lane >> 4;
        bf16* As = (bf16*)arena;             // 16 x 72
        bf16* Bs = (bf16*)(arena + 2304);    // 256 x 72

        const int arow = tid >> 4, akc = (tid & 15) << 2;
        const float* axp = x + (size_t)(m0 + arow) * CD + akc;
        int brow[8], bkc[8];
        const float* bsrc[8];
#pragma unroll
        for (int kk = 0; kk < 8; ++kk) {
            int v = tid + kk * 256;
            brow[kk] = v >> 3; bkc[kk] = (v & 7) << 3;
            bsrc[kk] = ((brow[kk] < 128) ? (wdq + (size_t)brow[kk] * CD)
                                         : (wdkv + (size_t)(brow[kk] - 128) * CD)) + bkc[kk];
        }

        float4 pA = *(const float4*)(axp);
        float4 pB0[8], pB1[8];
#pragma unroll
        for (int kk = 0; kk < 8; ++kk) {
            pB0[kk] = *(const float4*)(bsrc[kk]);
            pB1[kk] = *(const float4*)(bsrc[kk] + 4);
        }

        f32x4 acc[4];
#pragma unroll
        for (int nb = 0; nb < 4; ++nb) acc[nb] = (f32x4){0.f, 0.f, 0.f, 0.f};

        for (int k0 = 0; k0 < CD; k0 += 64) {
            __syncthreads();
            st4(As + arow * 72 + akc, pA);
#pragma unroll
            for (int kk = 0; kk < 8; ++kk)
                st8(Bs + brow[kk] * 72 + bkc[kk], cvt8(pB0[kk], pB1[kk]));
            __syncthreads();
            if (k0 + 64 < CD) {
                pA = *(const float4*)(axp + k0 + 64);
#pragma unroll
                for (int kk = 0; kk < 8; ++kk) {
                    pB0[kk] = *(const float4*)(bsrc[kk] + k0 + 64);
                    pB1[kk] = *(const float4*)(bsrc[kk] + k0 + 68);
                }
            }
            short8 aF[2];
#pragma unroll
            for (int kf = 0; kf < 2; ++kf)
                aF[kf] = ld8(As + m16 * 72 + kf * 32 + g * 8);
#pragma unroll
            for (int nb = 0; nb < 4; ++nb)
#pragma unroll
                for (int kf = 0; kf < 2; ++kf) {
                    short8 bF = ld8(Bs + (w * 64 + nb * 16 + m16) * 72 + kf * 32 + g * 8);
                    acc[nb] = __builtin_amdgcn_mfma_f32_16x16x32_bf16(aF[kf], bF, acc[nb], 0, 0, 0);
                }
        }

#pragma unroll
        for (int nb = 0; nb < 4; ++nb)
#pragma unroll
            for (int r = 0; r < 4; ++r) {
                int t = m0 + g * 4 + r;
                int col = w * 64 + nb * 16 + m16;
                float v = acc[nb][r];
                if (col < 128) {
                    q1_bf[(size_t)t * QLD + col] = __float2bfloat16(v);
                } else {
                    int l = col - 128;
                    ckv_out[(size_t)t * KVLD + l] = v;
                    bf16 hv = __float2bfloat16(v);
                    ckv_bf[(size_t)t * KVLD + l] = hv;
                    int b = t >> 11, tl = t & 2047;
                    ckvT_bf[((size_t)b * KVLD + l) * TD + tl] = hv;
                }
            }
    } else if (blk < 512) {
        // ================= Et ================================================
        const int b2 = blk - 256;
        const int h = b2 >> 4, lb = b2 & 15;
        float* m1s = (float*)arena;
        for (int v = tid; v < 1024; v += 256) {
            int p = v >> 3, lq = v & 7;
            float t0[8];
#pragma unroll
            for (int part = 0; part < 8; ++part)
                t0[part] = m1p[(size_t)part * 16384 + (size_t)p * 128 + lb * 8 + lq];
            float s0 = 0.f;
#pragma unroll
            for (int part = 0; part < 8; ++part) s0 += t0[part];
            m1s[v] = s0;
        }
        __syncthreads();
        const int lq = tid >> 5, i4 = (tid & 31) << 2;
        const float* Gh = G + (size_t)h * 16384;
        float4 acc = make_float4(0.f, 0.f, 0.f, 0.f);
        for (int p0 = 0; p0 < 128; p0 += 8) {
            float4 g[8]; float a[8];
#pragma unroll
            for (int u = 0; u < 8; ++u) {
                g[u] = *(const float4*)(Gh + (p0 + u) * 128 + i4);
                a[u] = m1s[(p0 + u) * 8 + lq];
            }
#pragma unroll
            for (int u = 0; u < 8; ++u) {
                acc.x = fmaf(a[u], g[u].x, acc.x);
                acc.y = fmaf(a[u], g[u].y, acc.y);
                acc.z = fmaf(a[u], g[u].z, acc.z);
                acc.w = fmaf(a[u], g[u].w, acc.w);
            }
        }
        const float sc = 0.1803368801f;  // 0.125 * log2(e): softmax in exp2 domain
        const int l = lb * 8 + lq;
        st4(Et_bf + ((size_t)h * 128 + l) * 128 + i4,
            make_float4(sc * acc.x, sc * acc.y, sc * acc.z, sc * acc.w));
    } else {
        // ================= veffT =============================================
        const int b3 = blk - 512;
        const int cc0 = b3 * 4;
        float* woS = (float*)arena;
        float* wuvS = (float*)arena + 4096;
#pragma unroll
        for (int k = 0; k < 4; ++k)
            ((float4*)woS)[tid + k * 256] = ((const float4*)(wo + (size_t)cc0 * CD))[tid + k * 256];

        const int r = tid >> 6;
        const int lh = tid & 63;
        float4 pf[8];
#pragma unroll
        for (int t = 0; t < 8; ++t)
            pf[t] = ((const float4*)wuv)[t * 256 + tid];

        float a0 = 0.f, a1 = 0.f;
        for (int ch = 0; ch < 16; ++ch) {
            __syncthreads();
#pragma unroll
            for (int t = 0; t < 8; ++t)
                ((float4*)wuvS)[t * 256 + tid] = pf[t];
            __syncthreads();
            if (ch < 15) {
#pragma unroll
                for (int t = 0; t < 8; ++t)
                    pf[t] = ((const float4*)wuv)[(ch + 1) * 2048 + t * 256 + tid];
            }
            const float* wr = woS + r * 1024 + ch * 64;
            const float2* vv = (const float2*)wuvS + lh;
            for (int cb = 0; cb < 64; cb += 8) {
                float wv[8]; float2 v[8];
#pragma unroll
                for (int u = 0; u < 8; ++u) {
                    wv[u] = wr[cb + u];
                    v[u] = vv[(cb + u) * 64];
                }
#pragma unroll
                for (int u = 0; u < 8; ++u) {
                    a0 = fmaf(wv[u], v[u].x, a0);
                    a1 = fmaf(wv[u], v[u].y, a1);
                }
            }
        }
        union { short2 s; bf16 h2[2]; } u;
        u.h2[0] = __float2bfloat16(a0);
        u.h2[1] = __float2bfloat16(a1);
        *(short2*)(veffT_bf + (size_t)(cc0 + r) * KVLD + lh * 2) = u.s;
    }
}

// ---------- MFMA flash attention: paired q-tiles, 8-wave blocks ----------
// r6 changes: (1) prologue MFMA operands swapped -> ql writeback is 8 st4f
// (8B contiguous) instead of 32 scalar 2B scattered stores (bank conflicts);
// (2) defer-max rescale (THR=8 in exp2 domain): skip the 36-reg cx rescale
// unless the running max grows by >8 (P bounded by 2^8; bf16 rel-err same).
__global__ __launch_bounds__(512, 4) void k_flash(const bf16* __restrict__ Q1_bf,
                                                  const bf16* __restrict__ Et_bf,
                                                  const bf16* __restrict__ ckv_bf,
                                                  const bf16* __restrict__ ckvT_bf,
                                                  const bf16* __restrict__ veffT_bf,
                                                  float* __restrict__ yout) {
    const int h = blockIdx.x & 15;
    const int b = blockIdx.x >> 4;
    const int qlo = blockIdx.y;          // 0..15
    const int qhi = 31 - qlo;            // 16..31
    const int tid = threadIdx.x;         // 0..511
    const int w = tid >> 6;              // 0..7
    const int ws = w >> 2;               // 0 = hi set, 1 = lo set
    const int wq = w & 3;                // wave within set
    const int lane = tid & 63;
    const int m16 = lane & 15;
    const int g = lane >> 4;
    const int myqt = ws ? qlo : qhi;
    const int row0 = myqt * 64;

    __shared__ __align__(16) short smem_raw[28288];
    bf16* smem = (bf16*)smem_raw;
    bf16* kvN = smem;                    // 64 x 136
    bf16* kvT = smem + 8704;             // 144 x 72 (rows 128..143 = ones)
    bf16* pS  = smem + 19072 + w * 1152; // per-wave 16 x 72, [q][s]
    bf16* bufLo = kvT;                   // prologue alias: 64 x 136
    bf16* vT = smem + 19072;             // epilogue alias: 64 x 136 (pS region)

    {
        const bf16 one = __float2bfloat16(1.0f);
        for (int idx = tid; idx < 16 * 72; idx += 512)
            kvT[9216 + idx] = one;
    }

    // ---- prologue: ql = Q1_tile @ E[h], swapped-operand form ----
    {
        const bf16* q1hi = Q1_bf + ((size_t)(b * TD + qhi * 64)) * QLD;
        const bf16* q1lo = Q1_bf + ((size_t)(b * TD + qlo * 64)) * QLD;
#pragma unroll
        for (int k = 0; k < 2; ++k) {
            int v = tid + k * 512;
            int row = v >> 4, cv = (v & 15) << 3;
            st8(kvN + row * 136 + cv, ld8(q1hi + row * QLD + cv));
            st8(bufLo + row * 136 + cv, ld8(q1lo + row * QLD + cv));
        }
    }
    __syncthreads();
    bf16* myQ1 = ws ? bufLo : kvN;
    {
        short8 aq[4];
#pragma unroll
        for (int kf = 0; kf < 4; ++kf)
            aq[kf] = ld8(myQ1 + (wq * 16 + m16) * 136 + kf * 32 + g * 8);
        const bf16* Eh = Et_bf + (size_t)h * QLD * KVLD;
        f32x4 qc[8];
#pragma unroll
        for (int nb = 0; nb < 8; ++nb) qc[nb] = (f32x4){0.f, 0.f, 0.f, 0.f};
#pragma unroll
        for (int nb = 0; nb < 8; ++nb)
#pragma unroll
            for (int kf = 0; kf < 4; ++kf) {
                short8 bq = ld8(Eh + (nb * 16 + m16) * QLD + kf * 32 + g * 8);
                // swapped: A = E-row (l), B = Q1-row (q) -> lane holds
                // ql[q = wq*16+m16][l = nb*16 + g*4 + r]
                qc[nb] = __builtin_amdgcn_mfma_f32_16x16x32_bf16(bq, aq[kf], qc[nb], 0, 0, 0);
            }
        __syncthreads();  // all waves done reading Q1 buffers
#pragma unroll
        for (int nb = 0; nb < 8; ++nb)
            st4f(myQ1 + (wq * 16 + m16) * 136 + nb * 16 + g * 4, qc[nb]);
    }
    __syncthreads();
    short8 qlA[4];
#pragma unroll
    for (int kf = 0; kf < 4; ++kf)
        qlA[kf] = ld8(myQ1 + (wq * 16 + m16) * 136 + kf * 32 + g * 8);

    // ---- main loop ----
    f32x4 cx[9];
#pragma unroll
    for (int nb = 0; nb < 9; ++nb) cx[nb] = (f32x4){0.f, 0.f, 0.f, 0.f};
    float mrow = -INFINITY;
    const int rg = row0 + wq * 16 + m16;

    const bf16* ckb = ckv_bf + (size_t)b * TD * KVLD;
    const bf16* ckTb = ckvT_bf + (size_t)b * KVLD * TD;

    int nrow[2], ncol[2], trow[2], tcol[2];
#pragma unroll
    for (int k = 0; k < 2; ++k) {
        int v = tid + k * 512;
        nrow[k] = v >> 4; ncol[k] = (v & 15) << 3;
        trow[k] = v >> 3; tcol[k] = (v & 7) << 3;
    }
    short8 pfN[2], pfT[2];
#pragma unroll
    for (int k = 0; k < 2; ++k) {
        pfN[k] = ld8(ckb + (size_t)nrow[k] * KVLD + ncol[k]);
        pfT[k] = ld8(ckTb + (size_t)trow[k] * TD + tcol[k]);
    }

    for (int tile = 0; tile <= qhi; ++tile) {
        const int s0 = tile * 64;
        __syncthreads();
#pragma unroll
        for (int k = 0; k < 2; ++k) {
            st8(kvN + nrow[k] * 136 + ncol[k], pfN[k]);
            st8(kvT + trow[k] * 72 + tcol[k], pfT[k]);
        }
        __syncthreads();
        if (tile < qhi) {
            const int s1 = s0 + 64;
#pragma unroll
            for (int k = 0; k < 2; ++k) {
                pfN[k] = ld8(ckb + (size_t)(s1 + nrow[k]) * KVLD + ncol[k]);
                pfT[k] = ld8(ckTb + (size_t)trow[k] * TD + s1 + tcol[k]);
            }
        }

        if (ws == 0 || tile <= qlo) {
            f32x4 sa[4];
#pragma unroll
            for (int nb = 0; nb < 4; ++nb) sa[nb] = (f32x4){0.f, 0.f, 0.f, 0.f};
#pragma unroll
            for (int nb = 0; nb < 4; ++nb)
#pragma unroll
                for (int kf = 0; kf < 4; ++kf) {
                    short8 ak = ld8(kvN + (nb * 16 + m16) * 136 + kf * 32 + g * 8);
                    sa[nb] = __builtin_amdgcn_mfma_f32_16x16x32_bf16(ak, qlA[kf], sa[nb], 0, 0, 0);
                }

            if (tile == myqt) {
#pragma unroll
                for (int nb = 0; nb < 4; ++nb)
#pragma unroll
                    for (int r = 0; r < 4; ++r) {
                        int sg = s0 + nb * 16 + g * 4 + r;
                        if (sg > rg) sa[nb][r] = -INFINITY;
                    }
            }

            // online softmax with defer-max (THR = 8 in exp2 domain)
            float mloc = sa[0][0];
#pragma unroll
            for (int nb = 0; nb < 4; ++nb)
#pragma unroll
                for (int r = 0; r < 4; ++r) mloc = fmaxf(mloc, sa[nb][r]);
            mloc = fmaxf(mloc, __shfl_xor(mloc, 16));
            mloc = fmaxf(mloc, __shfl_xor(mloc, 32));
            if (__any(mloc > mrow + 8.f)) {
                float mt = fmaxf(mrow, mloc);
                float al = exp2f(mrow - mt);
                mrow = mt;
#pragma unroll
                for (int nb = 0; nb < 9; ++nb)
#pragma unroll
                    for (int r = 0; r < 4; ++r) cx[nb][r] *= al;
            }

            // P^T -> pS[q][s]: contiguous b64 writes
#pragma unroll
            for (int nb = 0; nb < 4; ++nb) {
                float4 p4;
                p4.x = exp2f(sa[nb][0] - mrow);
                p4.y = exp2f(sa[nb][1] - mrow);
                p4.z = exp2f(sa[nb][2] - mrow);
                p4.w = exp2f(sa[nb][3] - mrow);
                st4(pS + m16 * 72 + nb * 16 + g * 4, p4);
            }
            __builtin_amdgcn_wave_barrier();

            short8 pA[2];
#pragma unroll
            for (int kf = 0; kf < 2; ++kf)
                pA[kf] = ld8(pS + m16 * 72 + kf * 32 + g * 8);
#pragma unroll
            for (int nb = 0; nb < 9; ++nb)
#pragma unroll
                for (int kf = 0; kf < 2; ++kf) {
                    short8 av = ld8(kvT + (nb * 16 + m16) * 72 + kf * 32 + g * 8);
                    cx[nb] = __builtin_amdgcn_mfma_f32_16x16x32_bf16(av, pA[kf], cx[nb], 0, 0, 0);
                }
        }
    }

    // ---- epilogue ----
    float invl = 1.f / cx[8][0];
#pragma unroll
    for (int nb = 0; nb < 8; ++nb)
#pragma unroll
        for (int r = 0; r < 4; ++r) cx[nb][r] *= invl;
    __syncthreads();
    bf16* ctxS = ws ? bufLo : kvN;
#pragma unroll
    for (int nb = 0; nb < 8; ++nb)
        st4f(ctxS + (wq * 16 + m16) * 136 + nb * 16 + g * 4, cx[nb]);
    {
        const bf16* vsrc = veffT_bf + (size_t)h * HSD * KVLD;
#pragma unroll
        for (int k = 0; k < 2; ++k) {
            int v = tid + k * 512;
            int row = v >> 4, cv = (v & 15) << 3;
            st8(vT + row * 136 + cv, ld8(vsrc + row * KVLD + cv));
        }
    }
    __syncthreads();

    short8 cB[4];
#pragma unroll
    for (int kf = 0; kf < 4; ++kf)
        cB[kf] = ld8(ctxS + (wq * 16 + m16) * 136 + kf * 32 + g * 8);
    f32x4 ya[4];
#pragma unroll
    for (int nb = 0; nb < 4; ++nb) ya[nb] = (f32x4){0.f, 0.f, 0.f, 0.f};
#pragma unroll
    for (int nb = 0; nb < 4; ++nb)
#pragma unroll
        for (int kf = 0; kf < 4; ++kf) {
            short8 av = ld8(vT + (nb * 16 + m16) * 136 + kf * 32 + g * 8);
            ya[nb] = __builtin_amdgcn_mfma_f32_16x16x32_bf16(av, cB[kf], ya[nb], 0, 0, 0);
        }
    float* yo = yout + ((size_t)b * TD + rg) * CD + h * HSD;
#pragma unroll
    for (int nb = 0; nb < 4; ++nb)
        *(float4*)(yo + nb * 16 + g * 4) = *(float4*)&ya[nb];
}

extern "C" void kernel_launch(void* const* d_in, const int* in_sizes, int n_in,
                              void* d_out, int out_size, void* d_ws, size_t ws_size,
                              hipStream_t stream) {
    const float* x    = (const float*)d_in[0];
    const float* wdq  = (const float*)d_in[1];
    const float* wuq  = (const float*)d_in[2];
    const float* wdkv = (const float*)d_in[3];
    const float* wuk  = (const float*)d_in[4];
    const float* wuv  = (const float*)d_in[5];
    const float* wo   = (const float*)d_in[6];
    float* yout = (float*)d_out;                   // (B,T,C) fp32
    float* ckv_out = yout + (size_t)BD * TD * CD;  // (B,T,KVL) fp32

    float* ws = (float*)d_ws;
    float* M1P = ws;                                    // 131072 f  (8 partials)
    float* G   = M1P + 131072;                          // 262144 f  [h][p][i]
    bf16* Et_bf    = (bf16*)(G + 262144);               // 262144 bf16 [h][l][i]
    bf16* veffT_bf = Et_bf + 262144;                    // 131072 bf16 [h*64+d][l]
    bf16* ckv_bf   = veffT_bf + 131072;                 // 524288 bf16 [b][t][l]
    bf16* ckvT_bf  = ckv_bf + 524288;                   // 524288 bf16 [b][l][t]
    bf16* Q1_bf    = ckvT_bf + 524288;                  // 524288 bf16 [b][t][i]

    k_pre <<<256, 256, 0, stream>>>(wuq, wuk, wdq, M1P, G);
    k_main<<<768, 256, 0, stream>>>(x, wdq, wdkv, M1P, G, wuv, wo,
                                    Q1_bf, ckv_out, ckv_bf, ckvT_bf, Et_bf, veffT_bf);

    dim3 grid(32, 16);
    k_flash<<<grid, 512, 0, stream>>>(Q1_bf, Et_bf, ckv_bf, ckvT_bf, veffT_bf, yout);
}

// Round 7
// 221.104 us; speedup vs baseline: 1.1146x; 1.1146x over previous
//
#include <hip/hip_runtime.h>
#include <hip/hip_bf16.h>

typedef __hip_bfloat16 bf16;
typedef __attribute__((ext_vector_type(8))) short short8;
typedef __attribute__((ext_vector_type(4))) float f32x4;

#define NHD 16
#define HSD 64
#define KVLD 128
#define QLD 128
#define CD 1024
#define BD 2
#define TD 2048

__device__ __forceinline__ short8 ld8(const bf16* p) { return *(const short8*)p; }
__device__ __forceinline__ void st8(bf16* p, short8 v) { *(short8*)p = v; }

__device__ __forceinline__ void st4(bf16* p, float4 a) {
    union { short4 s; bf16 h[4]; } u;
    u.h[0] = __float2bfloat16(a.x); u.h[1] = __float2bfloat16(a.y);
    u.h[2] = __float2bfloat16(a.z); u.h[3] = __float2bfloat16(a.w);
    *(short4*)p = u.s;
}
__device__ __forceinline__ void st4f(bf16* p, f32x4 a) {
    union { short4 s; bf16 h[4]; } u;
    u.h[0] = __float2bfloat16(a[0]); u.h[1] = __float2bfloat16(a[1]);
    u.h[2] = __float2bfloat16(a[2]); u.h[3] = __float2bfloat16(a[3]);
    *(short4*)p = u.s;
}

// ---------------------------------------------------------------------------
// Launch 1: k_pre — 320 blocks, batch-8 register load groups (r5 structure:
// proj-from-bf16-panel was strictly better than inline convert, r6 A/B).
//   [0,128):   M1 partials  m1p[part](i,j) = sum_{c chunk} wuq(c,i)*wuk(c,j)
//   [128,256): G[h](p,i) = sum_{d<64} wdq(p, h*64+d) * wuq(h*64+d, i)
//   [256,320): convert [Wdq|Wdkv] -> bf16 panel
// ---------------------------------------------------------------------------
__global__ __launch_bounds__(256) void k_pre(const float* __restrict__ wuq,
                                             const float* __restrict__ wuk,
                                             const float* __restrict__ wdq,
                                             const float* __restrict__ wdkv,
                                             float* __restrict__ m1p,
                                             float* __restrict__ G,
                                             bf16* __restrict__ wqkv_bf) {
    const int b = blockIdx.x;
    const int tid = threadIdx.x;
    if (b < 128) {
        const int part = b >> 4, ig = b & 15;
        const int i = ig * 8 + (tid >> 5);
        const int j4 = (tid & 31) << 2;
        const float* wq = wuq + (size_t)part * 128 * QLD;
        const float* wk = wuk + (size_t)part * 128 * KVLD;
        float4 acc = make_float4(0.f, 0.f, 0.f, 0.f);
        for (int c0 = 0; c0 < 128; c0 += 8) {
            float a[8]; float4 kv[8];
#pragma unroll
            for (int u = 0; u < 8; ++u) {
                a[u] = wq[(c0 + u) * QLD + i];
                kv[u] = *(const float4*)(wk + (c0 + u) * KVLD + j4);
            }
#pragma unroll
            for (int u = 0; u < 8; ++u) {
                acc.x = fmaf(a[u], kv[u].x, acc.x);
                acc.y = fmaf(a[u], kv[u].y, acc.y);
                acc.z = fmaf(a[u], kv[u].z, acc.z);
                acc.w = fmaf(a[u], kv[u].w, acc.w);
            }
        }
        *(float4*)(m1p + (size_t)part * 16384 + (size_t)i * 128 + j4) = acc;
    } else if (b < 256) {
        const int b1 = b - 128;
        const int h = b1 >> 3, p8 = b1 & 7;
        const int p = p8 * 16 + (tid >> 4);
        const int i8 = (tid & 15) << 3;
        float acc[8];
#pragma unroll
        for (int t = 0; t < 8; ++t) acc[t] = 0.f;
        const float* wdqp = wdq + (size_t)p * CD + h * 64;
        const float* wuqh = wuq + (size_t)(h * 64) * QLD + i8;
        for (int d0 = 0; d0 < 64; d0 += 8) {
            float a[8]; float4 b0[8], b1v[8];
#pragma unroll
            for (int u = 0; u < 8; ++u) {
                a[u] = wdqp[d0 + u];
                b0[u] = *(const float4*)(wuqh + (d0 + u) * QLD);
                b1v[u] = *(const float4*)(wuqh + (d0 + u) * QLD + 4);
            }
#pragma unroll
            for (int u = 0; u < 8; ++u) {
                acc[0] = fmaf(a[u], b0[u].x, acc[0]);  acc[1] = fmaf(a[u], b0[u].y, acc[1]);
                acc[2] = fmaf(a[u], b0[u].z, acc[2]);  acc[3] = fmaf(a[u], b0[u].w, acc[3]);
                acc[4] = fmaf(a[u], b1v[u].x, acc[4]); acc[5] = fmaf(a[u], b1v[u].y, acc[5]);
                acc[6] = fmaf(a[u], b1v[u].z, acc[6]); acc[7] = fmaf(a[u], b1v[u].w, acc[7]);
            }
        }
        float* dst = G + (size_t)h * 16384 + (size_t)p * 128 + i8;
        *(float4*)dst = make_float4(acc[0], acc[1], acc[2], acc[3]);
        *(float4*)(dst + 4) = make_float4(acc[4], acc[5], acc[6], acc[7]);
    } else {
        const int r = (b - 256) * 4 + (tid >> 6);
        const int lane = tid & 63;
        const float* src = (r < 128) ? (wdq + (size_t)r * CD) : (wdkv + (size_t)(r - 128) * CD);
        float4 f[4];
#pragma unroll
        for (int k = 0; k < 4; ++k) f[k] = ((const float4*)src)[lane + k * 64];
#pragma unroll
        for (int k = 0; k < 4; ++k)
            st4(wqkv_bf + (size_t)r * CD + (lane + k * 64) * 4, f[k]);
    }
}

// ---------------------------------------------------------------------------
// Launch 2: k_main — 768 blocks, three concurrent roles.
//   [0,256):   proj GEMM [Q1|ckv] = x @ [Wdq|Wdkv]^T from bf16 panel;
//              ckvT written as packed 8B short4 (was 2048 scalar 2B stores
//              at 4KB stride -> partial-line RMW; r6 WRITE_SIZE evidence)
//   [256,512): Et_h = scale * (M1^T @ G_h); batch-8 loads
//   [512,768): veffT = Wo @ Wuv; wuv LDS-chunked, reg double-buffered, batch-8
// ---------------------------------------------------------------------------
__global__ __launch_bounds__(256) void k_main(const float* __restrict__ x,
                                              const bf16* __restrict__ wqkv_bf,
                                              const float* __restrict__ m1p,
                                              const float* __restrict__ G,
                                              const float* __restrict__ wuv,
                                              const float* __restrict__ wo,
                                              bf16* __restrict__ q1_bf,
                                              float* __restrict__ ckv_out,
                                              bf16* __restrict__ ckv_bf,
                                              bf16* __restrict__ ckvT_bf,
                                              bf16* __restrict__ Et_bf,
                                              bf16* __restrict__ veffT_bf) {
    __shared__ __align__(16) char arena[49152];
    const int blk = blockIdx.x;
    const int tid = threadIdx.x;

    if (blk < 256) {
        // ================= proj (panel loads + reg-prefetch) =================
        const int m0 = blk * 16;
        const int w = tid >> 6, lane = tid & 63, m16 = lane & 15, g = lane >> 4;
        bf16* As = (bf16*)arena;             // 16 x 72
        bf16* Bs = (bf16*)(arena + 2304);    // 256 x 72

        const int arow = tid >> 4, akc = (tid & 15) << 2;
        const float* axp = x + (size_t)(m0 + arow) * CD + akc;
        int brow[8], bkc[8];
#pragma unroll
        for (int kk = 0; kk < 8; ++kk) {
            int v = tid + kk * 256;
            brow[kk] = v >> 3; bkc[kk] = (v & 7) << 3;
        }

        float4 pA = *(const float4*)(axp);
        short8 pB[8];
#pragma unroll
        for (int kk = 0; kk < 8; ++kk)
            pB[kk] = ld8(wqkv_bf + (size_t)brow[kk] * CD + bkc[kk]);

        f32x4 acc[4];
#pragma unroll
        for (int nb = 0; nb < 4; ++nb) acc[nb] = (f32x4){0.f, 0.f, 0.f, 0.f};

        for (int k0 = 0; k0 < CD; k0 += 64) {
            __syncthreads();
            st4(As + arow * 72 + akc, pA);
#pragma unroll
            for (int kk = 0; kk < 8; ++kk)
                st8(Bs + brow[kk] * 72 + bkc[kk], pB[kk]);
            __syncthreads();
            if (k0 + 64 < CD) {
                pA = *(const float4*)(axp + k0 + 64);
#pragma unroll
                for (int kk = 0; kk < 8; ++kk)
                    pB[kk] = ld8(wqkv_bf + (size_t)brow[kk] * CD + k0 + 64 + bkc[kk]);
            }
            short8 aF[2];
#pragma unroll
            for (int kf = 0; kf < 2; ++kf)
                aF[kf] = ld8(As + m16 * 72 + kf * 32 + g * 8);
#pragma unroll
            for (int nb = 0; nb < 4; ++nb)
#pragma unroll
                for (int kf = 0; kf < 2; ++kf) {
                    short8 bF = ld8(Bs + (w * 64 + nb * 16 + m16) * 72 + kf * 32 + g * 8);
                    acc[nb] = __builtin_amdgcn_mfma_f32_16x16x32_bf16(aF[kf], bF, acc[nb], 0, 0, 0);
                }
        }

        const int bb = m0 >> 11;            // batch index (block never straddles)
        const int tl0 = (m0 & 2047) + g * 4;
#pragma unroll
        for (int nb = 0; nb < 4; ++nb) {
            int col = w * 64 + nb * 16 + m16;
            if (col < 128) {
#pragma unroll
                for (int r = 0; r < 4; ++r)
                    q1_bf[(size_t)(m0 + g * 4 + r) * QLD + col] = __float2bfloat16(acc[nb][r]);
            } else {
                int l = col - 128;
                union { short4 s; bf16 h[4]; } pk;
#pragma unroll
                for (int r = 0; r < 4; ++r) {
                    int t = m0 + g * 4 + r;
                    float v = acc[nb][r];
                    ckv_out[(size_t)t * KVLD + l] = v;
                    bf16 hv = __float2bfloat16(v);
                    ckv_bf[(size_t)t * KVLD + l] = hv;
                    pk.h[r] = hv;
                }
                *(short4*)(ckvT_bf + ((size_t)bb * KVLD + l) * TD + tl0) = pk.s;
            }
        }
    } else if (blk < 512) {
        // ================= Et ================================================
        const int b2 = blk - 256;
        const int h = b2 >> 4, lb = b2 & 15;
        float* m1s = (float*)arena;
        for (int v = tid; v < 1024; v += 256) {
            int p = v >> 3, lq = v & 7;
            float t0[8];
#pragma unroll
            for (int part = 0; part < 8; ++part)
                t0[part] = m1p[(size_t)part * 16384 + (size_t)p * 128 + lb * 8 + lq];
            float s0 = 0.f;
#pragma unroll
            for (int part = 0; part < 8; ++part) s0 += t0[part];
            m1s[v] = s0;
        }
        __syncthreads();
        const int lq = tid >> 5, i4 = (tid & 31) << 2;
        const float* Gh = G + (size_t)h * 16384;
        float4 acc = make_float4(0.f, 0.f, 0.f, 0.f);
        for (int p0 = 0; p0 < 128; p0 += 8) {
            float4 g[8]; float a[8];
#pragma unroll
            for (int u = 0; u < 8; ++u) {
                g[u] = *(const float4*)(Gh + (p0 + u) * 128 + i4);
                a[u] = m1s[(p0 + u) * 8 + lq];
            }
#pragma unroll
            for (int u = 0; u < 8; ++u) {
                acc.x = fmaf(a[u], g[u].x, acc.x);
                acc.y = fmaf(a[u], g[u].y, acc.y);
                acc.z = fmaf(a[u], g[u].z, acc.z);
                acc.w = fmaf(a[u], g[u].w, acc.w);
            }
        }
        const float sc = 0.1803368801f;  // 0.125 * log2(e): softmax in exp2 domain
        const int l = lb * 8 + lq;
        st4(Et_bf + ((size_t)h * 128 + l) * 128 + i4,
            make_float4(sc * acc.x, sc * acc.y, sc * acc.z, sc * acc.w));
    } else {
        // ================= veffT =============================================
        const int b3 = blk - 512;
        const int cc0 = b3 * 4;
        float* woS = (float*)arena;
        float* wuvS = (float*)arena + 4096;
#pragma unroll
        for (int k = 0; k < 4; ++k)
            ((float4*)woS)[tid + k * 256] = ((const float4*)(wo + (size_t)cc0 * CD))[tid + k * 256];

        const int r = tid >> 6;
        const int lh = tid & 63;
        float4 pf[8];
#pragma unroll
        for (int t = 0; t < 8; ++t)
            pf[t] = ((const float4*)wuv)[t * 256 + tid];

        float a0 = 0.f, a1 = 0.f;
        for (int ch = 0; ch < 16; ++ch) {
            __syncthreads();
#pragma unroll
            for (int t = 0; t < 8; ++t)
                ((float4*)wuvS)[t * 256 + tid] = pf[t];
            __syncthreads();
            if (ch < 15) {
#pragma unroll
                for (int t = 0; t < 8; ++t)
                    pf[t] = ((const float4*)wuv)[(ch + 1) * 2048 + t * 256 + tid];
            }
            const float* wr = woS + r * 1024 + ch * 64;
            const float2* vv = (const float2*)wuvS + lh;
            for (int cb = 0; cb < 64; cb += 8) {
                float wv[8]; float2 v[8];
#pragma unroll
                for (int u = 0; u < 8; ++u) {
                    wv[u] = wr[cb + u];
                    v[u] = vv[(cb + u) * 64];
                }
#pragma unroll
                for (int u = 0; u < 8; ++u) {
                    a0 = fmaf(wv[u], v[u].x, a0);
                    a1 = fmaf(wv[u], v[u].y, a1);
                }
            }
        }
        union { short2 s; bf16 h2[2]; } u;
        u.h2[0] = __float2bfloat16(a0);
        u.h2[1] = __float2bfloat16(a1);
        *(short2*)(veffT_bf + (size_t)(cc0 + r) * KVLD + lh * 2) = u.s;
    }
}

// ---------- MFMA flash attention: paired q-tiles, 8-wave blocks ----------
// r6 flash retained: (1) swapped-operand prologue (ql writeback = 8 st4f
// contiguous instead of 32 scalar scattered 2B stores); (2) defer-max
// rescale THR=8 in exp2 domain (P bounded by 2^8; bf16 rel-err unchanged).
__global__ __launch_bounds__(512, 4) void k_flash(const bf16* __restrict__ Q1_bf,
                                                  const bf16* __restrict__ Et_bf,
                                                  const bf16* __restrict__ ckv_bf,
                                                  const bf16* __restrict__ ckvT_bf,
                                                  const bf16* __restrict__ veffT_bf,
                                                  float* __restrict__ yout) {
    const int h = blockIdx.x & 15;
    const int b = blockIdx.x >> 4;
    const int qlo = blockIdx.y;          // 0..15
    const int qhi = 31 - qlo;            // 16..31
    const int tid = threadIdx.x;         // 0..511
    const int w = tid >> 6;              // 0..7
    const int ws = w >> 2;               // 0 = hi set, 1 = lo set
    const int wq = w & 3;                // wave within set
    const int lane = tid & 63;
    const int m16 = lane & 15;
    const int g = lane >> 4;
    const int myqt = ws ? qlo : qhi;
    const int row0 = myqt * 64;

    __shared__ __align__(16) short smem_raw[28288];
    bf16* smem = (bf16*)smem_raw;
    bf16* kvN = smem;                    // 64 x 136
    bf16* kvT = smem + 8704;             // 144 x 72 (rows 128..143 = ones)
    bf16* pS  = smem + 19072 + w * 1152; // per-wave 16 x 72, [q][s]
    bf16* bufLo = kvT;                   // prologue alias: 64 x 136
    bf16* vT = smem + 19072;             // epilogue alias: 64 x 136 (pS region)

    {
        const bf16 one = __float2bfloat16(1.0f);
        for (int idx = tid; idx < 16 * 72; idx += 512)
            kvT[9216 + idx] = one;
    }

    // ---- prologue: ql = Q1_tile @ E[h], swapped-operand form ----
    {
        const bf16* q1hi = Q1_bf + ((size_t)(b * TD + qhi * 64)) * QLD;
        const bf16* q1lo = Q1_bf + ((size_t)(b * TD + qlo * 64)) * QLD;
#pragma unroll
        for (int k = 0; k < 2; ++k) {
            int v = tid + k * 512;
            int row = v >> 4, cv = (v & 15) << 3;
            st8(kvN + row * 136 + cv, ld8(q1hi + row * QLD + cv));
            st8(bufLo + row * 136 + cv, ld8(q1lo + row * QLD + cv));
        }
    }
    __syncthreads();
    bf16* myQ1 = ws ? bufLo : kvN;
    {
        short8 aq[4];
#pragma unroll
        for (int kf = 0; kf < 4; ++kf)
            aq[kf] = ld8(myQ1 + (wq * 16 + m16) * 136 + kf * 32 + g * 8);
        const bf16* Eh = Et_bf + (size_t)h * QLD * KVLD;
        f32x4 qc[8];
#pragma unroll
        for (int nb = 0; nb < 8; ++nb) qc[nb] = (f32x4){0.f, 0.f, 0.f, 0.f};
#pragma unroll
        for (int nb = 0; nb < 8; ++nb)
#pragma unroll
            for (int kf = 0; kf < 4; ++kf) {
                short8 bq = ld8(Eh + (nb * 16 + m16) * QLD + kf * 32 + g * 8);
                // swapped: lane holds ql[q = wq*16+m16][l = nb*16 + g*4 + r]
                qc[nb] = __builtin_amdgcn_mfma_f32_16x16x32_bf16(bq, aq[kf], qc[nb], 0, 0, 0);
            }
        __syncthreads();  // all waves done reading Q1 buffers
#pragma unroll
        for (int nb = 0; nb < 8; ++nb)
            st4f(myQ1 + (wq * 16 + m16) * 136 + nb * 16 + g * 4, qc[nb]);
    }
    __syncthreads();
    short8 qlA[4];
#pragma unroll
    for (int kf = 0; kf < 4; ++kf)
        qlA[kf] = ld8(myQ1 + (wq * 16 + m16) * 136 + kf * 32 + g * 8);

    // ---- main loop ----
    f32x4 cx[9];
#pragma unroll
    for (int nb = 0; nb < 9; ++nb) cx[nb] = (f32x4){0.f, 0.f, 0.f, 0.f};
    float mrow = -INFINITY;
    const int rg = row0 + wq * 16 + m16;

    const bf16* ckb = ckv_bf + (size_t)b * TD * KVLD;
    const bf16* ckTb = ckvT_bf + (size_t)b * KVLD * TD;

    int nrow[2], ncol[2], trow[2], tcol[2];
#pragma unroll
    for (int k = 0; k < 2; ++k) {
        int v = tid + k * 512;
        nrow[k] = v >> 4; ncol[k] = (v & 15) << 3;
        trow[k] = v >> 3; tcol[k] = (v & 7) << 3;
    }
    short8 pfN[2], pfT[2];
#pragma unroll
    for (int k = 0; k < 2; ++k) {
        pfN[k] = ld8(ckb + (size_t)nrow[k] * KVLD + ncol[k]);
        pfT[k] = ld8(ckTb + (size_t)trow[k] * TD + tcol[k]);
    }

    for (int tile = 0; tile <= qhi; ++tile) {
        const int s0 = tile * 64;
        __syncthreads();
#pragma unroll
        for (int k = 0; k < 2; ++k) {
            st8(kvN + nrow[k] * 136 + ncol[k], pfN[k]);
            st8(kvT + trow[k] * 72 + tcol[k], pfT[k]);
        }
        __syncthreads();
        if (tile < qhi) {
            const int s1 = s0 + 64;
#pragma unroll
            for (int k = 0; k < 2; ++k) {
                pfN[k] = ld8(ckb + (size_t)(s1 + nrow[k]) * KVLD + ncol[k]);
                pfT[k] = ld8(ckTb + (size_t)trow[k] * TD + s1 + tcol[k]);
            }
        }

        if (ws == 0 || tile <= qlo) {
            f32x4 sa[4];
#pragma unroll
            for (int nb = 0; nb < 4; ++nb) sa[nb] = (f32x4){0.f, 0.f, 0.f, 0.f};
#pragma unroll
            for (int nb = 0; nb < 4; ++nb)
#pragma unroll
                for (int kf = 0; kf < 4; ++kf) {
                    short8 ak = ld8(kvN + (nb * 16 + m16) * 136 + kf * 32 + g * 8);
                    sa[nb] = __builtin_amdgcn_mfma_f32_16x16x32_bf16(ak, qlA[kf], sa[nb], 0, 0, 0);
                }

            if (tile == myqt) {
#pragma unroll
                for (int nb = 0; nb < 4; ++nb)
#pragma unroll
                    for (int r = 0; r < 4; ++r) {
                        int sg = s0 + nb * 16 + g * 4 + r;
                        if (sg > rg) sa[nb][r] = -INFINITY;
                    }
            }

            // online softmax with defer-max (THR = 8 in exp2 domain)
            float mloc = sa[0][0];
#pragma unroll
            for (int nb = 0; nb < 4; ++nb)
#pragma unroll
                for (int r = 0; r < 4; ++r) mloc = fmaxf(mloc, sa[nb][r]);
            mloc = fmaxf(mloc, __shfl_xor(mloc, 16));
            mloc = fmaxf(mloc, __shfl_xor(mloc, 32));
            if (__any(mloc > mrow + 8.f)) {
                float mt = fmaxf(mrow, mloc);
                float al = exp2f(mrow - mt);
                mrow = mt;
#pragma unroll
                for (int nb = 0; nb < 9; ++nb)
#pragma unroll
                    for (int r = 0; r < 4; ++r) cx[nb][r] *= al;
            }

            // P^T -> pS[q][s]: contiguous b64 writes
#pragma unroll
            for (int nb = 0; nb < 4; ++nb) {
                float4 p4;
                p4.x = exp2f(sa[nb][0] - mrow);
                p4.y = exp2f(sa[nb][1] - mrow);
                p4.z = exp2f(sa[nb][2] - mrow);
                p4.w = exp2f(sa[nb][3] - mrow);
                st4(pS + m16 * 72 + nb * 16 + g * 4, p4);
            }
            __builtin_amdgcn_wave_barrier();

            short8 pA[2];
#pragma unroll
            for (int kf = 0; kf < 2; ++kf)
                pA[kf] = ld8(pS + m16 * 72 + kf * 32 + g * 8);
#pragma unroll
            for (int nb = 0; nb < 9; ++nb)
#pragma unroll
                for (int kf = 0; kf < 2; ++kf) {
                    short8 av = ld8(kvT + (nb * 16 + m16) * 72 + kf * 32 + g * 8);
                    cx[nb] = __builtin_amdgcn_mfma_f32_16x16x32_bf16(av, pA[kf], cx[nb], 0, 0, 0);
                }
        }
    }

    // ---- epilogue ----
    float invl = 1.f / cx[8][0];
#pragma unroll
    for (int nb = 0; nb < 8; ++nb)
#pragma unroll
        for (int r = 0; r < 4; ++r) cx[nb][r] *= invl;
    __syncthreads();
    bf16* ctxS = ws ? bufLo : kvN;
#pragma unroll
    for (int nb = 0; nb < 8; ++nb)
        st4f(ctxS + (wq * 16 + m16) * 136 + nb * 16 + g * 4, cx[nb]);
    {
        const bf16* vsrc = veffT_bf + (size_t)h * HSD * KVLD;
#pragma unroll
        for (int k = 0; k < 2; ++k) {
            int v = tid + k * 512;
            int row = v >> 4, cv = (v & 15) << 3;
            st8(vT + row * 136 + cv, ld8(vsrc + row * KVLD + cv));
        }
    }
    __syncthreads();

    short8 cB[4];
#pragma unroll
    for (int kf = 0; kf < 4; ++kf)
        cB[kf] = ld8(ctxS + (wq * 16 + m16) * 136 + kf * 32 + g * 8);
    f32x4 ya[4];
#pragma unroll
    for (int nb = 0; nb < 4; ++nb) ya[nb] = (f32x4){0.f, 0.f, 0.f, 0.f};
#pragma unroll
    for (int nb = 0; nb < 4; ++nb)
#pragma unroll
        for (int kf = 0; kf < 4; ++kf) {
            short8 av = ld8(vT + (nb * 16 + m16) * 136 + kf * 32 + g * 8);
            ya[nb] = __builtin_amdgcn_mfma_f32_16x16x32_bf16(av, cB[kf], ya[nb], 0, 0, 0);
        }
    float* yo = yout + ((size_t)b * TD + rg) * CD + h * HSD;
#pragma unroll
    for (int nb = 0; nb < 4; ++nb)
        *(float4*)(yo + nb * 16 + g * 4) = *(float4*)&ya[nb];
}

extern "C" void kernel_launch(void* const* d_in, const int* in_sizes, int n_in,
                              void* d_out, int out_size, void* d_ws, size_t ws_size,
                              hipStream_t stream) {
    const float* x    = (const float*)d_in[0];
    const float* wdq  = (const float*)d_in[1];
    const float* wuq  = (const float*)d_in[2];
    const float* wdkv = (const float*)d_in[3];
    const float* wuk  = (const float*)d_in[4];
    const float* wuv  = (const float*)d_in[5];
    const float* wo   = (const float*)d_in[6];
    float* yout = (float*)d_out;                   // (B,T,C) fp32
    float* ckv_out = yout + (size_t)BD * TD * CD;  // (B,T,KVL) fp32

    // ws: ~6.0 MB
    float* ws = (float*)d_ws;
    float* M1P = ws;                                    // 131072 f  (8 partials)
    float* G   = M1P + 131072;                          // 262144 f  [h][p][i]
    bf16* wqkv_bf  = (bf16*)(G + 262144);               // 262144 bf16 [row][c]
    bf16* Et_bf    = wqkv_bf + 262144;                  // 262144 bf16 [h][l][i]
    bf16* veffT_bf = Et_bf + 262144;                    // 131072 bf16 [h*64+d][l]
    bf16* ckv_bf   = veffT_bf + 131072;                 // 524288 bf16 [b][t][l]
    bf16* ckvT_bf  = ckv_bf + 524288;                   // 524288 bf16 [b][l][t]
    bf16* Q1_bf    = ckvT_bf + 524288;                  // 524288 bf16 [b][t][i]

    k_pre <<<320, 256, 0, stream>>>(wuq, wuk, wdq, wdkv, M1P, G, wqkv_bf);
    k_main<<<768, 256, 0, stream>>>(x, wqkv_bf, M1P, G, wuv, wo,
                                    Q1_bf, ckv_out, ckv_bf, ckvT_bf, Et_bf, veffT_bf);

    dim3 grid(32, 16);
    k_flash<<<grid, 512, 0, stream>>>(Q1_bf, Et_bf, ckv_bf, ckvT_bf, veffT_bf, yout);
}